// Round 5
// baseline (35198.679 us; speedup 1.0000x reference)
//
#include <hip/hip_runtime.h>
#include <math.h>

#define H 2048
#define S 8192
#define RPB 8            // hidden rows per block
#define NBLK (H / RPB)   // 256 blocks = 256 CUs

// ---------------------------------------------------------------------------
// GEMM: U[t][j] = sum_k X[t][k] * Wxh[j][k]   (NT, fp32 vector ALU). ~1 ms.
// ---------------------------------------------------------------------------
__global__ __launch_bounds__(256) void gemm_xw(const float* __restrict__ X,
                                               const float* __restrict__ W,
                                               float* __restrict__ U) {
    __shared__ float As[16][64];   // [k][t]
    __shared__ float Bs[16][64];   // [k][j]
    const int tid = threadIdx.x;
    const int t0 = blockIdx.x * 64;
    const int j0 = blockIdx.y * 64;
    const int tx = tid & 15, ty = tid >> 4;

    float acc[4][4] = {};
    const int lr = tid >> 2;
    const int lk = (tid & 3) * 4;

    for (int k0 = 0; k0 < H; k0 += 16) {
        float4 a = *(const float4*)&X[(size_t)(t0 + lr) * H + k0 + lk];
        float4 b = *(const float4*)&W[(size_t)(j0 + lr) * H + k0 + lk];
        As[lk + 0][lr] = a.x; As[lk + 1][lr] = a.y; As[lk + 2][lr] = a.z; As[lk + 3][lr] = a.w;
        Bs[lk + 0][lr] = b.x; Bs[lk + 1][lr] = b.y; Bs[lk + 2][lr] = b.z; Bs[lk + 3][lr] = b.w;
        __syncthreads();
#pragma unroll
        for (int kk = 0; kk < 16; ++kk) {
            float4 av = *(const float4*)&As[kk][ty * 4];
            float4 bv = *(const float4*)&Bs[kk][tx * 4];
            float aa[4] = {av.x, av.y, av.z, av.w};
            float bb[4] = {bv.x, bv.y, bv.z, bv.w};
#pragma unroll
            for (int i = 0; i < 4; ++i)
#pragma unroll
                for (int j = 0; j < 4; ++j)
                    acc[i][j] += aa[i] * bb[j];
        }
        __syncthreads();
    }
#pragma unroll
    for (int i = 0; i < 4; ++i) {
        float4 v = {acc[i][0], acc[i][1], acc[i][2], acc[i][3]};
        *(float4*)&U[(size_t)(t0 + ty * 4 + i) * H + j0 + tx * 4] = v;
    }
}

// ---------------------------------------------------------------------------
// Init: zero tagged h double-buffer (2*H u64) + block-tag array (2*NBLK u64).
// All-zero => (tag=0, h=0): h0 for step 0; parity-1 tags (0) never match t>=1.
// ---------------------------------------------------------------------------
__global__ void init_ws(unsigned long long* __restrict__ ws) {
    int i = blockIdx.x * blockDim.x + threadIdx.x;
    if (i < 2 * H + 2 * NBLK) ws[i] = 0ull;
}

#define AG_LOAD(p)     __hip_atomic_load((p), __ATOMIC_RELAXED, __HIP_MEMORY_SCOPE_AGENT)
#define AG_STORE(p, v) __hip_atomic_store((p), (v), __ATOMIC_RELAXED, __HIP_MEMORY_SCOPE_AGENT)

// ---------------------------------------------------------------------------
// Persistent recurrent kernel. Round-5 structure:
//  * POLL FOOTPRINT 8x SMALLER: consumers spin on a per-block tag array
//    (256 x 8B = 32 cache lines chip-wide) instead of re-scanning the
//    2048-word tagged h vector (256 lines) every iteration. Round-3/4
//    polling pushed ~10 TB/s of LLC reads, congesting the fabric the
//    publish stores must traverse.
//  * Tagged h data (tag<<32 | bits) is then bulk-read ONCE per step with
//    verify-retry; embedded tags make btag/data store reordering safe
//    without any release fence on the publish path.
//  * W_hh lives in REGISTERS (16 float4/thread): dot reads only h from LDS
//    (half the LDS traffic), LDS down to 16 KB.
//  * Keep: publish-before-out[], U prefetched one step ahead, s_sleep spin.
// Skew bound: a block publishes tag t+2 only after verifying all tag-t data,
// which needs all blocks to have published t+1, which needs all to have
// consumed tag t => max skew 1 step => 2-deep buffers race-free.
// ---------------------------------------------------------------------------
__global__ __launch_bounds__(256) void rnn_recur(float* __restrict__ out,
                                                 const float* __restrict__ Whh,
                                                 const float* __restrict__ bias,
                                                 unsigned long long* __restrict__ hvt,
                                                 unsigned long long* __restrict__ btag) {
    __shared__ float hs[2][H];      // 16 KB ping-pong h_{t-1}
    const int tid = threadIdx.x;
    const int bid = blockIdx.x;
    const int r0 = bid * RPB;
    const int g    = tid >> 5;      // row group 0..7
    const int lane = tid & 31;
    const int row  = r0 + g;

    // W_hh row slice into registers: wreg[i] = W[row][4*(lane + i*32) ..+3]
    // (coalesced 16B/lane loads at init; read every step at zero LDS cost).
    float4 wreg[16];
    {
        const float4* wrow = (const float4*)&Whh[(size_t)row * H];
#pragma unroll
        for (int i = 0; i < 16; ++i) wreg[i] = wrow[lane + i * 32];
    }

    const float bb = bias[row];
    float u_next = out[row];        // U for step 0
    float hT = 0.0f;

    for (int t = 0; t < S; ++t) {
        const float u_val = u_next;
        if (t + 1 < S)              // next U prefetch hides under the wait
            u_next = out[(size_t)(t + 1) * H + row];

        // ---- phase 1: spin on ONE per-block tag word (thread tid watches
        // block tid). Tiny footprint; s_sleep throttles fabric pressure. ----
        {
            unsigned long long* bt = &btag[(size_t)(t & 1) * NBLK + tid];
            while (AG_LOAD(bt) != (unsigned long long)t)
                __builtin_amdgcn_s_sleep(1);
        }
        __syncthreads();   // all 256 btags seen == t

        // ---- phase 2: bulk-read tagged h once, verify embedded tags ----
        unsigned long long* hb = &hvt[(size_t)(t & 1) * H];
        float* hdst = hs[t & 1];
        const unsigned int tag = (unsigned int)t;
        unsigned int pend = 0xFFu;
        while (pend) {
            unsigned long long vv[8];
#pragma unroll
            for (int i = 0; i < 8; ++i)
                if (pend & (1u << i))
                    vv[i] = AG_LOAD(&hb[i * 256 + tid]);
#pragma unroll
            for (int i = 0; i < 8; ++i)
                if (pend & (1u << i))
                    if ((unsigned int)(vv[i] >> 32) == tag) {
                        hdst[i * 256 + tid] = __uint_as_float((unsigned int)vv[i]);
                        pend &= ~(1u << i);
                    }
        }
        __syncthreads();   // hs[t&1] complete

        // ---- dot: W from regs, h from LDS (16 b128 reads/thread) ----
        const float4* hv = (const float4*)hdst;
        float dot = 0.f;
#pragma unroll
        for (int i = 0; i < 16; ++i) {
            float4 h4 = hv[lane + i * 32];
            dot += wreg[i].x * h4.x + wreg[i].y * h4.y
                 + wreg[i].z * h4.z + wreg[i].w * h4.w;
        }
#pragma unroll
        for (int off = 16; off; off >>= 1)
            dot += __shfl_down(dot, off, 32);

        if (lane == 0) {
            float val = tanhf(dot + u_val + bb);
            // publish data first (critical path), then the btag hint, then
            // the off-path out[] write.
            unsigned long long pk =
                ((unsigned long long)(unsigned int)(t + 1) << 32) |
                (unsigned long long)__float_as_uint(val);
            AG_STORE(&hvt[(size_t)((t + 1) & 1) * H + row], pk);
            if (tid == 0)
                AG_STORE(&btag[(size_t)((t + 1) & 1) * NBLK + bid],
                         (unsigned long long)(t + 1));
            out[(size_t)t * H + row] = val;
            hT = val;
        }
    }
    if (lane == 0) out[(size_t)S * H + row] = hT;   // h_T
}

extern "C" void kernel_launch(void* const* d_in, const int* in_sizes, int n_in,
                              void* d_out, int out_size, void* d_ws, size_t ws_size,
                              hipStream_t stream) {
    const float* X    = (const float*)d_in[0];  // (8192, 2048)
    const float* Wxh  = (const float*)d_in[1];  // (2048, 2048)
    const float* Whh  = (const float*)d_in[2];  // (2048, 2048)
    const float* bias = (const float*)d_in[3];  // (2048,)
    float* out = (float*)d_out;
    unsigned long long* hvt  = (unsigned long long*)d_ws;          // 2*H tagged words
    unsigned long long* btag = hvt + 2 * H;                        // 2*NBLK block tags

    init_ws<<<(2 * H + 2 * NBLK + 255) / 256, 256, 0, stream>>>(hvt);

    dim3 ggrid(S / 64, H / 64);
    gemm_xw<<<ggrid, 256, 0, stream>>>(X, Wxh, out);

    void* args[] = {(void*)&out, (void*)&Whh, (void*)&bias, (void*)&hvt, (void*)&btag};
    hipLaunchCooperativeKernel((void*)rnn_recur, dim3(NBLK), dim3(256), args, 0, stream);
}